// Round 1
// baseline (226.604 us; speedup 1.0000x reference)
//
#include <hip/hip_runtime.h>
#include <hip/hip_bf16.h>

#define SEQ    4096
#define DIM    512
#define DIM3   1536
#define NH     16
#define HD     32
#define CHUNK  64
#define NCHUNK (SEQ / CHUNK)

// ---------------------------------------------------------------------------
// Kernel 1: qkv = x @ W_qkv   (M=4096, N=1536, K=512), f32 tiled GEMM
// ---------------------------------------------------------------------------
#define BM 64
#define BN 64
#define BK 16
__global__ __launch_bounds__(256) void gl_gemm_f32(
    const float* __restrict__ A, const float* __restrict__ B,
    float* __restrict__ C, int M, int N, int K) {
  __shared__ float As[BK][BM + 1];
  __shared__ float Bs[BK][BN + 1];
  const int bx = blockIdx.x;          // N tile
  const int by = blockIdx.y;          // M tile
  const int tid = threadIdx.x;
  const int tx = tid & 15;            // micro-tile col (4 cols)
  const int ty = tid >> 4;            // micro-tile row (4 rows)
  const int row0 = by * BM, col0 = bx * BN;
  float acc[4][4] = {};
  for (int k0 = 0; k0 < K; k0 += BK) {
    #pragma unroll
    for (int i = tid; i < BM * BK; i += 256) {
      int r = i >> 4, kk = i & 15;
      As[kk][r] = A[(size_t)(row0 + r) * K + k0 + kk];
    }
    #pragma unroll
    for (int i = tid; i < BK * BN; i += 256) {
      int kk = i >> 6, c = i & 63;
      Bs[kk][c] = B[(size_t)(k0 + kk) * N + col0 + c];
    }
    __syncthreads();
    #pragma unroll
    for (int kk = 0; kk < BK; ++kk) {
      float a[4], b[4];
      #pragma unroll
      for (int j = 0; j < 4; ++j) a[j] = As[kk][ty * 4 + j];
      #pragma unroll
      for (int j = 0; j < 4; ++j) b[j] = Bs[kk][tx * 4 + j];
      #pragma unroll
      for (int i = 0; i < 4; ++i)
        #pragma unroll
        for (int j = 0; j < 4; ++j) acc[i][j] += a[i] * b[j];
    }
    __syncthreads();
  }
  #pragma unroll
  for (int i = 0; i < 4; ++i)
    #pragma unroll
    for (int j = 0; j < 4; ++j)
      C[(size_t)(row0 + ty * 4 + i) * N + col0 + tx * 4 + j] = acc[i][j];
}

// ---------------------------------------------------------------------------
// Kernel 2: a_lin = x @ W_a + b_a ; gate = (a/|a|) * sigmoid(|a|)  (complex)
// gates stored as float2, layout [head][n]
// ---------------------------------------------------------------------------
__global__ __launch_bounds__(64) void gl_gate(
    const float* __restrict__ x, const float* __restrict__ Wa,
    const float* __restrict__ ba, float2* __restrict__ gates) {
  const int n = blockIdx.x;
  const int tid = threadIdx.x;
  __shared__ float xs[DIM];
  __shared__ float al[2 * NH];
  for (int i = tid; i < DIM; i += 64) xs[i] = x[(size_t)n * DIM + i];
  __syncthreads();
  if (tid < 2 * NH) {
    float dot = ba[tid];
    for (int k = 0; k < DIM; ++k) dot += xs[k] * Wa[(size_t)k * (2 * NH) + tid];
    al[tid] = dot;
  }
  __syncthreads();
  if (tid < NH) {
    float re = al[2 * tid], im = al[2 * tid + 1];
    float mag = sqrtf(re * re + im * im);
    float sig = 1.0f / (1.0f + expf(-mag));
    float2 g;
    if (mag < 1e-30f) {
      g = make_float2(0.5f, 0.0f);
    } else {
      float s = sig / mag;
      g = make_float2(re * s, im * s);
    }
    gates[(size_t)tid * SEQ + n] = g;
  }
}

// ---------------------------------------------------------------------------
// Kernel 3 (pass 1): per (head, chunk) local end-state S_loc (complex 32x32,
// zero-init) and cumulative gate product A_prod.
// Thread layout: tid*4 .. tid*4+3 state elements idx = d*32+e.
// ---------------------------------------------------------------------------
__global__ __launch_bounds__(256) void gl_pass1(
    const float* __restrict__ qkv, const float2* __restrict__ gates,
    float2* __restrict__ Sloc, float2* __restrict__ Aprod) {
  const int c = blockIdx.x;  // chunk
  const int h = blockIdx.y;  // head
  const int tid = threadIdx.x;
  __shared__ float ks[CHUNK][HD];
  __shared__ float vs[CHUNK][HD];
  __shared__ float2 as_[CHUNK];
  const int n0 = c * CHUNK;
  for (int i = tid; i < CHUNK * HD; i += 256) {
    int t = i >> 5, e = i & 31;
    size_t rowoff = (size_t)(n0 + t) * DIM3 + h * HD + e;
    ks[t][e] = qkv[rowoff + DIM];       // k block
    vs[t][e] = qkv[rowoff + 2 * DIM];   // v block
  }
  if (tid < CHUNK) as_[tid] = gates[(size_t)h * SEQ + n0 + tid];
  __syncthreads();

  const int base = tid * 4;
  const int d = base >> 5;
  const int e0 = base & 31;
  float sre[4] = {0, 0, 0, 0}, sim[4] = {0, 0, 0, 0};
  for (int t = 0; t < CHUNK; ++t) {
    float2 a = as_[t];
    float kd = ks[t][d];
    #pragma unroll
    for (int j = 0; j < 4; ++j) {
      float re = sre[j], im = sim[j];
      sre[j] = a.x * re - a.y * im + kd * vs[t][e0 + j];
      sim[j] = a.y * re + a.x * im;
    }
  }
  float2* outp = Sloc + (size_t)(h * NCHUNK + c) * (HD * HD);
  #pragma unroll
  for (int j = 0; j < 4; ++j) outp[base + j] = make_float2(sre[j], sim[j]);

  if (tid == 0) {
    float2 p = make_float2(1.0f, 0.0f);
    for (int t = 0; t < CHUNK; ++t) {
      float2 a = as_[t];
      p = make_float2(p.x * a.x - p.y * a.y, p.x * a.y + p.y * a.x);
    }
    Aprod[h * NCHUNK + c] = p;
  }
}

// ---------------------------------------------------------------------------
// Kernel 4: per-head sequential scan over chunk states:
//   S_in[c] = Aprod[c-1]*S_in[c-1] + S_loc[c-1],  S_in[0]=0
// ---------------------------------------------------------------------------
__global__ __launch_bounds__(256) void gl_scan_chunks(
    const float2* __restrict__ Sloc, const float2* __restrict__ Aprod,
    float2* __restrict__ Sin) {
  const int h = blockIdx.x;
  const int tid = threadIdx.x;
  float2 s[4] = {{0, 0}, {0, 0}, {0, 0}, {0, 0}};
  for (int c = 0; c < NCHUNK; ++c) {
    size_t off = (size_t)(h * NCHUNK + c) * (HD * HD) + tid * 4;
    #pragma unroll
    for (int j = 0; j < 4; ++j) Sin[off + j] = s[j];
    float2 a = Aprod[h * NCHUNK + c];
    #pragma unroll
    for (int j = 0; j < 4; ++j) {
      float2 l = Sloc[off + j];
      float re = s[j].x, im = s[j].y;
      s[j] = make_float2(a.x * re - a.y * im + l.x,
                         a.x * im + a.y * re + l.y);
    }
  }
}

// ---------------------------------------------------------------------------
// Kernel 5 (pass 2): replay each chunk with incoming state, emit outputs
//   o_n[e] = sum_d q_n[d] * Re(S_n)[d][e]
// Thread layout: tid = e*8 + dsub, thread owns d = dsub*4 .. dsub*4+3, col e.
// ---------------------------------------------------------------------------
__global__ __launch_bounds__(256) void gl_pass2(
    const float* __restrict__ qkv, const float2* __restrict__ gates,
    const float2* __restrict__ Sin, float* __restrict__ out) {
  const int c = blockIdx.x;
  const int h = blockIdx.y;
  const int tid = threadIdx.x;
  __shared__ float qs[CHUNK][HD];
  __shared__ float ks[CHUNK][HD];
  __shared__ float vs[CHUNK][HD];
  __shared__ float os[CHUNK][HD];
  __shared__ float2 as_[CHUNK];
  const int n0 = c * CHUNK;
  for (int i = tid; i < CHUNK * HD; i += 256) {
    int t = i >> 5, e = i & 31;
    size_t rowoff = (size_t)(n0 + t) * DIM3 + h * HD + e;
    qs[t][e] = qkv[rowoff];
    ks[t][e] = qkv[rowoff + DIM];
    vs[t][e] = qkv[rowoff + 2 * DIM];
  }
  if (tid < CHUNK) as_[tid] = gates[(size_t)h * SEQ + n0 + tid];
  __syncthreads();

  const int e = tid >> 3;     // 0..31
  const int dsub = tid & 7;   // 0..7
  const int d0 = dsub * 4;
  float sre[4], sim[4];
  const size_t soff = (size_t)(h * NCHUNK + c) * (HD * HD);
  #pragma unroll
  for (int j = 0; j < 4; ++j) {
    float2 sv = Sin[soff + (size_t)(d0 + j) * HD + e];
    sre[j] = sv.x;
    sim[j] = sv.y;
  }
  for (int t = 0; t < CHUNK; ++t) {
    float2 a = as_[t];
    float ve = vs[t][e];
    float partial = 0.0f;
    #pragma unroll
    for (int j = 0; j < 4; ++j) {
      float kd = ks[t][d0 + j];
      float re = sre[j], im = sim[j];
      sre[j] = a.x * re - a.y * im + kd * ve;
      sim[j] = a.y * re + a.x * im;
      partial += qs[t][d0 + j] * sre[j];
    }
    partial += __shfl_xor(partial, 1);
    partial += __shfl_xor(partial, 2);
    partial += __shfl_xor(partial, 4);
    if (dsub == 0) os[t][e] = partial;
  }
  __syncthreads();
  for (int i = tid; i < CHUNK * HD; i += 256) {
    int t = i >> 5, ee = i & 31;
    out[(size_t)(n0 + t) * DIM + h * HD + ee] = os[t][ee];
  }
}

// ---------------------------------------------------------------------------
extern "C" void kernel_launch(void* const* d_in, const int* in_sizes, int n_in,
                              void* d_out, int out_size, void* d_ws,
                              size_t ws_size, hipStream_t stream) {
  const float* x     = (const float*)d_in[0];   // (4096, 512)
  const float* W_qkv = (const float*)d_in[1];   // (512, 1536)
  const float* W_a   = (const float*)d_in[2];   // (512, 32)
  const float* b_a   = (const float*)d_in[3];   // (32,)
  float* out = (float*)d_out;                   // (4096, 512)

  char* ws = (char*)d_ws;
  float*  qkv   = (float*)ws;                               // 4096*1536*4 = 25165824 B
  float2* gates = (float2*)(ws + 25165824);                 // 16*4096*8   = 524288 B
  float2* Sloc  = (float2*)(ws + 25165824 + 524288);        // 1024*1024*8 = 8388608 B
  float2* Aprod = (float2*)(ws + 25165824 + 524288 + 8388608);        // 1024*8 = 8192 B
  float2* Sin   = (float2*)(ws + 25165824 + 524288 + 8388608 + 8192); // 8388608 B

  // 1. qkv GEMM
  gl_gemm_f32<<<dim3(DIM3 / BN, SEQ / BM), 256, 0, stream>>>(
      x, W_qkv, qkv, SEQ, DIM3, DIM);
  // 2. gates
  gl_gate<<<SEQ, 64, 0, stream>>>(x, W_a, b_a, gates);
  // 3. per-chunk local scan
  gl_pass1<<<dim3(NCHUNK, NH), 256, 0, stream>>>(qkv, gates, Sloc, Aprod);
  // 4. chunk-level scan
  gl_scan_chunks<<<NH, 256, 0, stream>>>(Sloc, Aprod, Sin);
  // 5. replay with incoming state, emit outputs
  gl_pass2<<<dim3(NCHUNK, NH), 256, 0, stream>>>(qkv, gates, Sin, out);
}

// Round 2
// 113.356 us; speedup vs baseline: 1.9991x; 1.9991x over previous
//
#include <hip/hip_runtime.h>
#include <hip/hip_bf16.h>

#define SEQ    4096
#define DIM    512
#define DIM3   1536
#define NH     16
#define HD     32
#define CHUNK  64
#define NCHUNK (SEQ / CHUNK)

typedef __attribute__((ext_vector_type(8))) short short8;
typedef __attribute__((ext_vector_type(4))) float f32x4;
typedef __attribute__((ext_vector_type(4))) unsigned short u16x4;

__device__ inline unsigned short f2bf(float f) {
  unsigned u = __builtin_bit_cast(unsigned, f);
  unsigned r = (u + 0x7fff + ((u >> 16) & 1)) >> 16;
  return (unsigned short)r;
}

// ---------------------------------------------------------------------------
// Conversion: x (4096x512 f32) -> bf16, 4 elems/thread
// ---------------------------------------------------------------------------
__global__ __launch_bounds__(256) void gl_cvt_x(
    const float4* __restrict__ x, u16x4* __restrict__ xb) {
  int i = blockIdx.x * 256 + threadIdx.x;
  float4 v = x[i];
  u16x4 o = {f2bf(v.x), f2bf(v.y), f2bf(v.z), f2bf(v.w)};
  xb[i] = o;
}

// ---------------------------------------------------------------------------
// Conversion + transpose: W_qkv (512x1536 f32) -> Wt (1536x512 bf16)
// ---------------------------------------------------------------------------
__global__ __launch_bounds__(256) void gl_cvt_wt(
    const float* __restrict__ W, unsigned short* __restrict__ Wt) {
  __shared__ float tile[32][33];
  const int bx = blockIdx.x;  // n tile (48)
  const int by = blockIdx.y;  // k tile (16)
  const int tx = threadIdx.x & 31, ty = threadIdx.x >> 5;  // ty 0..7
  for (int i = ty; i < 32; i += 8)
    tile[i][tx] = W[(size_t)(by * 32 + i) * DIM3 + bx * 32 + tx];
  __syncthreads();
  for (int i = ty; i < 32; i += 8)
    Wt[(size_t)(bx * 32 + i) * DIM + by * 32 + tx] = f2bf(tile[tx][i]);
}

// ---------------------------------------------------------------------------
// Kernel 1: qkv = x @ W_qkv via bf16 MFMA. A=[M][K] bf16, Bt=[N][K] bf16.
// 128x128 tile, BK=64, 4 waves; global_load_lds(16B) with linear LDS dest +
// inverse-swizzled global source; XOR-swizzled ds_read_b128 (conflict-free).
// ---------------------------------------------------------------------------
#define GBM 128
#define GBN 128
#define GBK 64
__global__ __launch_bounds__(256) void gl_gemm_mfma(
    const unsigned short* __restrict__ A, const unsigned short* __restrict__ Bt,
    float* __restrict__ C, int M, int N, int K) {
  __shared__ unsigned short As[GBM * GBK];  // 16 KB, row-major [128][64], swizzled slots
  __shared__ unsigned short Bs[GBN * GBK];  // 16 KB
  const int tid = threadIdx.x;
  const int row0 = blockIdx.y * GBM;
  const int col0 = blockIdx.x * GBN;
  const int wid = tid >> 6, lane = tid & 63;
  const int wr = wid >> 1, wc = wid & 1;
  const int lr = lane & 15, lg = lane >> 4;
  const char* AsB = (const char*)As;
  const char* BsB = (const char*)Bs;

  f32x4 acc[4][4] = {};

  for (int k0 = 0; k0 < K; k0 += GBK) {
    // stage A and B tiles: 16 KB each = 4 issues x 256 threads x 16 B
    #pragma unroll
    for (int i = 0; i < 4; ++i) {
      int byteoff = i * 4096 + tid * 16;
      int row = byteoff >> 7;              // 128 B per row
      int physslot = (byteoff >> 4) & 7;   // 16 B slots
      int logslot = physslot ^ (row & 7);  // inverse swizzle on source
      const unsigned short* gp = A + (size_t)(row0 + row) * K + k0 + logslot * 8;
      __builtin_amdgcn_global_load_lds(
          (const __attribute__((address_space(1))) void*)gp,
          (__attribute__((address_space(3))) void*)(AsB + byteoff), 16, 0, 0);
    }
    #pragma unroll
    for (int i = 0; i < 4; ++i) {
      int byteoff = i * 4096 + tid * 16;
      int row = byteoff >> 7;
      int physslot = (byteoff >> 4) & 7;
      int logslot = physslot ^ (row & 7);
      const unsigned short* gp = Bt + (size_t)(col0 + row) * K + k0 + logslot * 8;
      __builtin_amdgcn_global_load_lds(
          (const __attribute__((address_space(1))) void*)gp,
          (__attribute__((address_space(3))) void*)(BsB + byteoff), 16, 0, 0);
    }
    asm volatile("s_waitcnt vmcnt(0)" ::: "memory");
    __syncthreads();

    #pragma unroll
    for (int ks = 0; ks < 2; ++ks) {
      short8 af[4], bfr[4];
      #pragma unroll
      for (int m = 0; m < 4; ++m) {
        int row = wr * 64 + m * 16 + lr;
        int ps = (ks * 4 + lg) ^ (row & 7);
        af[m] = *(const short8*)(AsB + row * 128 + ps * 16);
      }
      #pragma unroll
      for (int n = 0; n < 4; ++n) {
        int col = wc * 64 + n * 16 + lr;
        int ps = (ks * 4 + lg) ^ (col & 7);
        bfr[n] = *(const short8*)(BsB + col * 128 + ps * 16);
      }
      #pragma unroll
      for (int m = 0; m < 4; ++m)
        #pragma unroll
        for (int n = 0; n < 4; ++n)
          acc[m][n] = __builtin_amdgcn_mfma_f32_16x16x32_bf16(
              af[m], bfr[n], acc[m][n], 0, 0, 0);
    }
    __syncthreads();
  }

  // C/D layout: col = lane&15, row = (lane>>4)*4 + reg  [m89/m91]
  #pragma unroll
  for (int m = 0; m < 4; ++m)
    #pragma unroll
    for (int n = 0; n < 4; ++n) {
      int grow0 = row0 + wr * 64 + m * 16 + lg * 4;
      int gcol = col0 + wc * 64 + n * 16 + lr;
      #pragma unroll
      for (int j = 0; j < 4; ++j)
        C[(size_t)(grow0 + j) * N + gcol] = acc[m][n][j];
    }
}

// ---------------------------------------------------------------------------
// Kernel 2: a_lin = x @ W_a + b_a ; gate = (a/|a|) * sigmoid(|a|)  (complex)
// gates stored as float2, layout [head][n]
// ---------------------------------------------------------------------------
__global__ __launch_bounds__(64) void gl_gate(
    const float* __restrict__ x, const float* __restrict__ Wa,
    const float* __restrict__ ba, float2* __restrict__ gates) {
  const int n = blockIdx.x;
  const int tid = threadIdx.x;
  __shared__ float xs[DIM];
  __shared__ float al[2 * NH];
  for (int i = tid; i < DIM; i += 64) xs[i] = x[(size_t)n * DIM + i];
  __syncthreads();
  if (tid < 2 * NH) {
    float dot = ba[tid];
    for (int k = 0; k < DIM; ++k) dot += xs[k] * Wa[(size_t)k * (2 * NH) + tid];
    al[tid] = dot;
  }
  __syncthreads();
  if (tid < NH) {
    float re = al[2 * tid], im = al[2 * tid + 1];
    float mag = sqrtf(re * re + im * im);
    float sig = 1.0f / (1.0f + expf(-mag));
    float2 g;
    if (mag < 1e-30f) {
      g = make_float2(0.5f, 0.0f);
    } else {
      float s = sig / mag;
      g = make_float2(re * s, im * s);
    }
    gates[(size_t)tid * SEQ + n] = g;
  }
}

// ---------------------------------------------------------------------------
// Kernel 3 (pass 1): per (head, chunk) local end-state S_loc (complex 32x32)
// and cumulative gate product A_prod.
// ---------------------------------------------------------------------------
__global__ __launch_bounds__(256) void gl_pass1(
    const float* __restrict__ qkv, const float2* __restrict__ gates,
    float2* __restrict__ Sloc, float2* __restrict__ Aprod) {
  const int c = blockIdx.x;
  const int h = blockIdx.y;
  const int tid = threadIdx.x;
  __shared__ float ks[CHUNK][HD];
  __shared__ float vs[CHUNK][HD];
  __shared__ float2 as_[CHUNK];
  const int n0 = c * CHUNK;
  for (int i = tid; i < CHUNK * HD; i += 256) {
    int t = i >> 5, e = i & 31;
    size_t rowoff = (size_t)(n0 + t) * DIM3 + h * HD + e;
    ks[t][e] = qkv[rowoff + DIM];
    vs[t][e] = qkv[rowoff + 2 * DIM];
  }
  if (tid < CHUNK) as_[tid] = gates[(size_t)h * SEQ + n0 + tid];
  __syncthreads();

  const int base = tid * 4;
  const int d = base >> 5;
  const int e0 = base & 31;
  float sre[4] = {0, 0, 0, 0}, sim[4] = {0, 0, 0, 0};
  for (int t = 0; t < CHUNK; ++t) {
    float2 a = as_[t];
    float kd = ks[t][d];
    #pragma unroll
    for (int j = 0; j < 4; ++j) {
      float re = sre[j], im = sim[j];
      sre[j] = a.x * re - a.y * im + kd * vs[t][e0 + j];
      sim[j] = a.y * re + a.x * im;
    }
  }
  float2* outp = Sloc + (size_t)(h * NCHUNK + c) * (HD * HD);
  #pragma unroll
  for (int j = 0; j < 4; ++j) outp[base + j] = make_float2(sre[j], sim[j]);

  if (tid == 0) {
    float2 p = make_float2(1.0f, 0.0f);
    for (int t = 0; t < CHUNK; ++t) {
      float2 a = as_[t];
      p = make_float2(p.x * a.x - p.y * a.y, p.x * a.y + p.y * a.x);
    }
    Aprod[h * NCHUNK + c] = p;
  }
}

// ---------------------------------------------------------------------------
// Kernel 4: per-head sequential scan over chunk states
// ---------------------------------------------------------------------------
__global__ __launch_bounds__(256) void gl_scan_chunks(
    const float2* __restrict__ Sloc, const float2* __restrict__ Aprod,
    float2* __restrict__ Sin) {
  const int h = blockIdx.x;
  const int tid = threadIdx.x;
  float2 s[4] = {{0, 0}, {0, 0}, {0, 0}, {0, 0}};
  for (int c = 0; c < NCHUNK; ++c) {
    size_t off = (size_t)(h * NCHUNK + c) * (HD * HD) + tid * 4;
    #pragma unroll
    for (int j = 0; j < 4; ++j) Sin[off + j] = s[j];
    float2 a = Aprod[h * NCHUNK + c];
    #pragma unroll
    for (int j = 0; j < 4; ++j) {
      float2 l = Sloc[off + j];
      float re = s[j].x, im = s[j].y;
      s[j] = make_float2(a.x * re - a.y * im + l.x,
                         a.x * im + a.y * re + l.y);
    }
  }
}

// ---------------------------------------------------------------------------
// Kernel 5 (pass 2): replay each chunk with incoming state, emit outputs
// ---------------------------------------------------------------------------
__global__ __launch_bounds__(256) void gl_pass2(
    const float* __restrict__ qkv, const float2* __restrict__ gates,
    const float2* __restrict__ Sin, float* __restrict__ out) {
  const int c = blockIdx.x;
  const int h = blockIdx.y;
  const int tid = threadIdx.x;
  __shared__ float qs[CHUNK][HD];
  __shared__ float ks[CHUNK][HD];
  __shared__ float vs[CHUNK][HD];
  __shared__ float os[CHUNK][HD];
  __shared__ float2 as_[CHUNK];
  const int n0 = c * CHUNK;
  for (int i = tid; i < CHUNK * HD; i += 256) {
    int t = i >> 5, e = i & 31;
    size_t rowoff = (size_t)(n0 + t) * DIM3 + h * HD + e;
    qs[t][e] = qkv[rowoff];
    ks[t][e] = qkv[rowoff + DIM];
    vs[t][e] = qkv[rowoff + 2 * DIM];
  }
  if (tid < CHUNK) as_[tid] = gates[(size_t)h * SEQ + n0 + tid];
  __syncthreads();

  const int e = tid >> 3;
  const int dsub = tid & 7;
  const int d0 = dsub * 4;
  float sre[4], sim[4];
  const size_t soff = (size_t)(h * NCHUNK + c) * (HD * HD);
  #pragma unroll
  for (int j = 0; j < 4; ++j) {
    float2 sv = Sin[soff + (size_t)(d0 + j) * HD + e];
    sre[j] = sv.x;
    sim[j] = sv.y;
  }
  for (int t = 0; t < CHUNK; ++t) {
    float2 a = as_[t];
    float ve = vs[t][e];
    float partial = 0.0f;
    #pragma unroll
    for (int j = 0; j < 4; ++j) {
      float kd = ks[t][d0 + j];
      float re = sre[j], im = sim[j];
      sre[j] = a.x * re - a.y * im + kd * ve;
      sim[j] = a.y * re + a.x * im;
      partial += qs[t][d0 + j] * sre[j];
    }
    partial += __shfl_xor(partial, 1);
    partial += __shfl_xor(partial, 2);
    partial += __shfl_xor(partial, 4);
    if (dsub == 0) os[t][e] = partial;
  }
  __syncthreads();
  for (int i = tid; i < CHUNK * HD; i += 256) {
    int t = i >> 5, ee = i & 31;
    out[(size_t)(n0 + t) * DIM + h * HD + ee] = os[t][ee];
  }
}

// ---------------------------------------------------------------------------
extern "C" void kernel_launch(void* const* d_in, const int* in_sizes, int n_in,
                              void* d_out, int out_size, void* d_ws,
                              size_t ws_size, hipStream_t stream) {
  const float* x     = (const float*)d_in[0];   // (4096, 512)
  const float* W_qkv = (const float*)d_in[1];   // (512, 1536)
  const float* W_a   = (const float*)d_in[2];   // (512, 32)
  const float* b_a   = (const float*)d_in[3];   // (32,)
  float* out = (float*)d_out;                   // (4096, 512)

  char* ws = (char*)d_ws;
  float*          qkv   = (float*)ws;                         // 25165824 B
  float2*         gates = (float2*)(ws + 25165824);           // 524288 B
  float2*         Sloc  = (float2*)(ws + 25690112);           // 8388608 B
  float2*         Aprod = (float2*)(ws + 34078720);           // 8192 B
  float2*         Sin   = (float2*)(ws + 34086912);           // 8388608 B
  unsigned short* xb    = (unsigned short*)(ws + 42475520);   // 4194304 B
  unsigned short* Wt    = (unsigned short*)(ws + 46669824);   // 1572864 B

  // 0. bf16 conversions
  gl_cvt_x<<<2048, 256, 0, stream>>>((const float4*)x, (u16x4*)xb);
  gl_cvt_wt<<<dim3(48, 16), 256, 0, stream>>>(W_qkv, Wt);
  // 1. qkv GEMM (MFMA bf16)
  gl_gemm_mfma<<<dim3(DIM3 / GBN, SEQ / GBM), 256, 0, stream>>>(
      xb, Wt, qkv, SEQ, DIM3, DIM);
  // 2. gates
  gl_gate<<<SEQ, 64, 0, stream>>>(x, W_a, b_a, gates);
  // 3. per-chunk local scan
  gl_pass1<<<dim3(NCHUNK, NH), 256, 0, stream>>>(qkv, gates, Sloc, Aprod);
  // 4. chunk-level scan
  gl_scan_chunks<<<NH, 256, 0, stream>>>(Sloc, Aprod, Sin);
  // 5. replay with incoming state, emit outputs
  gl_pass2<<<dim3(NCHUNK, NH), 256, 0, stream>>>(qkv, gates, Sin, out);
}

// Round 3
// 83.899 us; speedup vs baseline: 2.7009x; 1.3511x over previous
//
#include <hip/hip_runtime.h>
#include <hip/hip_bf16.h>

#define SEQ    4096
#define DIM    512
#define DIM3   1536
#define NH     16
#define HD     32
#define CHUNK  64
#define NCHUNK (SEQ / CHUNK)

typedef __attribute__((ext_vector_type(8))) short short8;
typedef __attribute__((ext_vector_type(4))) float f32x4;
typedef __attribute__((ext_vector_type(4))) unsigned short u16x4;

__device__ inline unsigned short f2bf(float f) {
  unsigned u = __builtin_bit_cast(unsigned, f);
  unsigned r = (u + 0x7fff + ((u >> 16) & 1)) >> 16;
  return (unsigned short)r;
}

// ---------------------------------------------------------------------------
// Kernel 0 (merged): x -> bf16 (blocks 0..2047); W_qkv -> Wt bf16 transposed
// (blocks 2048..2815)
// ---------------------------------------------------------------------------
__global__ __launch_bounds__(256) void gl_cvt(
    const float* __restrict__ x, const float* __restrict__ W,
    unsigned short* __restrict__ xb, unsigned short* __restrict__ Wt) {
  int b = blockIdx.x;
  if (b < 2048) {
    int i = b * 256 + threadIdx.x;
    float4 v = ((const float4*)x)[i];
    u16x4 o = {f2bf(v.x), f2bf(v.y), f2bf(v.z), f2bf(v.w)};
    ((u16x4*)xb)[i] = o;
  } else {
    b -= 2048;
    int bx = b % 48, by = b / 48;  // bx: n-tile, by: k-tile
    __shared__ float tile[32][33];
    int tx = threadIdx.x & 31, ty = threadIdx.x >> 5;
    for (int i = ty; i < 32; i += 8)
      tile[i][tx] = W[(size_t)(by * 32 + i) * DIM3 + bx * 32 + tx];
    __syncthreads();
    for (int i = ty; i < 32; i += 8)
      Wt[(size_t)(bx * 32 + i) * DIM + by * 32 + tx] = f2bf(tile[tx][i]);
  }
}

// ---------------------------------------------------------------------------
// Kernel 1: qkv = x @ W_qkv via bf16 MFMA. A=[M][K] bf16, Bt=[N][K] bf16.
// 128x128 tile, BK=64, 4 waves; global_load_lds(16B) linear dest +
// inverse-swizzled source; XOR-swizzled ds_read_b128 (conflict-free).
// ---------------------------------------------------------------------------
#define GBM 128
#define GBN 128
#define GBK 64
__global__ __launch_bounds__(256) void gl_gemm_mfma(
    const unsigned short* __restrict__ A, const unsigned short* __restrict__ Bt,
    float* __restrict__ C, int M, int N, int K) {
  __shared__ unsigned short As[GBM * GBK];
  __shared__ unsigned short Bs[GBN * GBK];
  const int tid = threadIdx.x;
  const int row0 = blockIdx.y * GBM;
  const int col0 = blockIdx.x * GBN;
  const int wid = tid >> 6, lane = tid & 63;
  const int wr = wid >> 1, wc = wid & 1;
  const int lr = lane & 15, lg = lane >> 4;
  const char* AsB = (const char*)As;
  const char* BsB = (const char*)Bs;

  f32x4 acc[4][4] = {};

  for (int k0 = 0; k0 < K; k0 += GBK) {
    #pragma unroll
    for (int i = 0; i < 4; ++i) {
      int byteoff = i * 4096 + tid * 16;
      int row = byteoff >> 7;
      int physslot = (byteoff >> 4) & 7;
      int logslot = physslot ^ (row & 7);
      const unsigned short* gp = A + (size_t)(row0 + row) * K + k0 + logslot * 8;
      __builtin_amdgcn_global_load_lds(
          (const __attribute__((address_space(1))) void*)gp,
          (__attribute__((address_space(3))) void*)(AsB + byteoff), 16, 0, 0);
    }
    #pragma unroll
    for (int i = 0; i < 4; ++i) {
      int byteoff = i * 4096 + tid * 16;
      int row = byteoff >> 7;
      int physslot = (byteoff >> 4) & 7;
      int logslot = physslot ^ (row & 7);
      const unsigned short* gp = Bt + (size_t)(col0 + row) * K + k0 + logslot * 8;
      __builtin_amdgcn_global_load_lds(
          (const __attribute__((address_space(1))) void*)gp,
          (__attribute__((address_space(3))) void*)(BsB + byteoff), 16, 0, 0);
    }
    asm volatile("s_waitcnt vmcnt(0)" ::: "memory");
    __syncthreads();

    #pragma unroll
    for (int ks = 0; ks < 2; ++ks) {
      short8 af[4], bfr[4];
      #pragma unroll
      for (int m = 0; m < 4; ++m) {
        int row = wr * 64 + m * 16 + lr;
        int ps = (ks * 4 + lg) ^ (row & 7);
        af[m] = *(const short8*)(AsB + row * 128 + ps * 16);
      }
      #pragma unroll
      for (int n = 0; n < 4; ++n) {
        int col = wc * 64 + n * 16 + lr;
        int ps = (ks * 4 + lg) ^ (col & 7);
        bfr[n] = *(const short8*)(BsB + col * 128 + ps * 16);
      }
      #pragma unroll
      for (int m = 0; m < 4; ++m)
        #pragma unroll
        for (int n = 0; n < 4; ++n)
          acc[m][n] = __builtin_amdgcn_mfma_f32_16x16x32_bf16(
              af[m], bfr[n], acc[m][n], 0, 0, 0);
    }
    __syncthreads();
  }

  #pragma unroll
  for (int m = 0; m < 4; ++m)
    #pragma unroll
    for (int n = 0; n < 4; ++n) {
      int grow0 = row0 + wr * 64 + m * 16 + lg * 4;
      int gcol = col0 + wc * 64 + n * 16 + lr;
      #pragma unroll
      for (int j = 0; j < 4; ++j)
        C[(size_t)(grow0 + j) * N + gcol] = acc[m][n][j];
    }
}

// ---------------------------------------------------------------------------
// Kernel 2: gates. 4 rows/block, full 256-thread utilization.
// a_lin kept in exact f32 (gate phase error compounds over decay horizon).
// ---------------------------------------------------------------------------
__global__ __launch_bounds__(256) void gl_gate(
    const float* __restrict__ x, const float* __restrict__ Wa,
    const float* __restrict__ ba, float2* __restrict__ gates) {
  const int n0 = blockIdx.x * 4;
  __shared__ float xs[4][DIM];
  __shared__ float red[4][8][32];
  const float4* xv = (const float4*)(x + (size_t)n0 * DIM);
  float4* xsv = (float4*)&xs[0][0];
  for (int i = threadIdx.x; i < 512; i += 256) xsv[i] = xv[i];
  __syncthreads();

  const int o = threadIdx.x & 31, s = threadIdx.x >> 5;
  float p[4] = {0, 0, 0, 0};
  for (int k = s * 64; k < s * 64 + 64; ++k) {
    float w = Wa[k * 32 + o];
    #pragma unroll
    for (int r = 0; r < 4; ++r) p[r] += xs[r][k] * w;
  }
  #pragma unroll
  for (int r = 0; r < 4; ++r) red[r][s][o] = p[r];
  __syncthreads();

  if (threadIdx.x < 128) {
    int r = threadIdx.x >> 5, oo = threadIdx.x & 31;
    float acc = ba[oo];
    #pragma unroll
    for (int ss = 0; ss < 8; ++ss) acc += red[r][ss][oo];
    red[r][0][oo] = acc;
  }
  __syncthreads();

  if (threadIdx.x < 64) {
    int r = threadIdx.x >> 4, h = threadIdx.x & 15;
    float re = red[r][0][2 * h], im = red[r][0][2 * h + 1];
    float mag = sqrtf(re * re + im * im);
    float sig = 1.0f / (1.0f + expf(-mag));
    float2 g;
    if (mag < 1e-30f) {
      g = make_float2(0.5f, 0.0f);
    } else {
      float sc = sig / mag;
      g = make_float2(re * sc, im * sc);
    }
    gates[(size_t)h * SEQ + n0 + r] = g;
  }
}

// ---------------------------------------------------------------------------
// Kernel 3 (pass 1): per (head, chunk) local end-state S_loc (complex 32x32)
// and cumulative gate product A_prod.
// ---------------------------------------------------------------------------
__global__ __launch_bounds__(256) void gl_pass1(
    const float* __restrict__ qkv, const float2* __restrict__ gates,
    float2* __restrict__ Sloc, float2* __restrict__ Aprod) {
  const int c = blockIdx.x;
  const int h = blockIdx.y;
  const int tid = threadIdx.x;
  __shared__ float ks[CHUNK][HD];
  __shared__ float vs[CHUNK][HD];
  __shared__ float2 as_[CHUNK];
  const int n0 = c * CHUNK;
  for (int i = tid; i < CHUNK * HD; i += 256) {
    int t = i >> 5, e = i & 31;
    size_t rowoff = (size_t)(n0 + t) * DIM3 + h * HD + e;
    ks[t][e] = qkv[rowoff + DIM];
    vs[t][e] = qkv[rowoff + 2 * DIM];
  }
  if (tid < CHUNK) as_[tid] = gates[(size_t)h * SEQ + n0 + tid];
  __syncthreads();

  const int base = tid * 4;
  const int d = base >> 5;
  const int e0 = base & 31;
  float sre[4] = {0, 0, 0, 0}, sim[4] = {0, 0, 0, 0};
  for (int t = 0; t < CHUNK; ++t) {
    float2 a = as_[t];
    float kd = ks[t][d];
    #pragma unroll
    for (int j = 0; j < 4; ++j) {
      float re = sre[j], im = sim[j];
      sre[j] = a.x * re - a.y * im + kd * vs[t][e0 + j];
      sim[j] = a.y * re + a.x * im;
    }
  }
  float2* outp = Sloc + (size_t)(h * NCHUNK + c) * (HD * HD);
  #pragma unroll
  for (int j = 0; j < 4; ++j) outp[base + j] = make_float2(sre[j], sim[j]);

  if (tid == 0) {
    float2 p = make_float2(1.0f, 0.0f);
    for (int t = 0; t < CHUNK; ++t) {
      float2 a = as_[t];
      p = make_float2(p.x * a.x - p.y * a.y, p.x * a.y + p.y * a.x);
    }
    Aprod[h * NCHUNK + c] = p;
  }
}

// ---------------------------------------------------------------------------
// Kernel 4: chunk-level scan, parallelized: 128 blocks (16 heads x 8 octants),
// 128 threads, 1 complex element/thread, 8-deep load batching for MLP.
// ---------------------------------------------------------------------------
__global__ __launch_bounds__(128) void gl_scan_chunks(
    const float2* __restrict__ Sloc, const float2* __restrict__ Aprod,
    float2* __restrict__ Sin) {
  const int h = blockIdx.x >> 3;
  const int oct = blockIdx.x & 7;
  const int elem = oct * 128 + threadIdx.x;
  const float2* SL = Sloc + (size_t)h * NCHUNK * (HD * HD) + elem;
  float2* SI = Sin + (size_t)h * NCHUNK * (HD * HD) + elem;
  const float2* AP = Aprod + h * NCHUNK;
  float2 s = make_float2(0.0f, 0.0f);
  for (int cg = 0; cg < NCHUNK; cg += 8) {
    float2 l[8], a[8];
    #pragma unroll
    for (int j = 0; j < 8; ++j) {
      l[j] = SL[(size_t)(cg + j) * (HD * HD)];
      a[j] = AP[cg + j];
    }
    #pragma unroll
    for (int j = 0; j < 8; ++j) {
      SI[(size_t)(cg + j) * (HD * HD)] = s;
      float re = s.x, im = s.y;
      s.x = a[j].x * re - a[j].y * im + l[j].x;
      s.y = a[j].x * im + a[j].y * re + l[j].y;
    }
  }
}

// ---------------------------------------------------------------------------
// Kernel 5 (pass 2): replay each chunk with incoming state, emit outputs
// ---------------------------------------------------------------------------
__global__ __launch_bounds__(256) void gl_pass2(
    const float* __restrict__ qkv, const float2* __restrict__ gates,
    const float2* __restrict__ Sin, float* __restrict__ out) {
  const int c = blockIdx.x;
  const int h = blockIdx.y;
  const int tid = threadIdx.x;
  __shared__ float qs[CHUNK][HD];
  __shared__ float ks[CHUNK][HD];
  __shared__ float vs[CHUNK][HD];
  __shared__ float os[CHUNK][HD];
  __shared__ float2 as_[CHUNK];
  const int n0 = c * CHUNK;
  for (int i = tid; i < CHUNK * HD; i += 256) {
    int t = i >> 5, e = i & 31;
    size_t rowoff = (size_t)(n0 + t) * DIM3 + h * HD + e;
    qs[t][e] = qkv[rowoff];
    ks[t][e] = qkv[rowoff + DIM];
    vs[t][e] = qkv[rowoff + 2 * DIM];
  }
  if (tid < CHUNK) as_[tid] = gates[(size_t)h * SEQ + n0 + tid];
  __syncthreads();

  const int e = tid >> 3;
  const int dsub = tid & 7;
  const int d0 = dsub * 4;
  float sre[4], sim[4];
  const size_t soff = (size_t)(h * NCHUNK + c) * (HD * HD);
  #pragma unroll
  for (int j = 0; j < 4; ++j) {
    float2 sv = Sin[soff + (size_t)(d0 + j) * HD + e];
    sre[j] = sv.x;
    sim[j] = sv.y;
  }
  for (int t = 0; t < CHUNK; ++t) {
    float2 a = as_[t];
    float ve = vs[t][e];
    float partial = 0.0f;
    #pragma unroll
    for (int j = 0; j < 4; ++j) {
      float kd = ks[t][d0 + j];
      float re = sre[j], im = sim[j];
      sre[j] = a.x * re - a.y * im + kd * ve;
      sim[j] = a.y * re + a.x * im;
      partial += qs[t][d0 + j] * sre[j];
    }
    partial += __shfl_xor(partial, 1);
    partial += __shfl_xor(partial, 2);
    partial += __shfl_xor(partial, 4);
    if (dsub == 0) os[t][e] = partial;
  }
  __syncthreads();
  for (int i = tid; i < CHUNK * HD; i += 256) {
    int t = i >> 5, ee = i & 31;
    out[(size_t)(n0 + t) * DIM + h * HD + ee] = os[t][ee];
  }
}

// ---------------------------------------------------------------------------
extern "C" void kernel_launch(void* const* d_in, const int* in_sizes, int n_in,
                              void* d_out, int out_size, void* d_ws,
                              size_t ws_size, hipStream_t stream) {
  const float* x     = (const float*)d_in[0];   // (4096, 512)
  const float* W_qkv = (const float*)d_in[1];   // (512, 1536)
  const float* W_a   = (const float*)d_in[2];   // (512, 32)
  const float* b_a   = (const float*)d_in[3];   // (32,)
  float* out = (float*)d_out;                   // (4096, 512)

  char* ws = (char*)d_ws;
  float*          qkv   = (float*)ws;                         // 25165824 B
  float2*         gates = (float2*)(ws + 25165824);           // 524288 B
  float2*         Sloc  = (float2*)(ws + 25690112);           // 8388608 B
  float2*         Aprod = (float2*)(ws + 34078720);           // 8192 B
  float2*         Sin   = (float2*)(ws + 34086912);           // 8388608 B
  unsigned short* xb    = (unsigned short*)(ws + 42475520);   // 4194304 B
  unsigned short* Wt    = (unsigned short*)(ws + 46669824);   // 1572864 B

  // 0. bf16 conversions (merged)
  gl_cvt<<<2816, 256, 0, stream>>>(x, W_qkv, xb, Wt);
  // 1. qkv GEMM (MFMA bf16)
  gl_gemm_mfma<<<dim3(DIM3 / GBN, SEQ / GBM), 256, 0, stream>>>(
      xb, Wt, qkv, SEQ, DIM3, DIM);
  // 2. gates (f32-exact a_lin)
  gl_gate<<<SEQ / 4, 256, 0, stream>>>(x, W_a, b_a, gates);
  // 3. per-chunk local scan
  gl_pass1<<<dim3(NCHUNK, NH), 256, 0, stream>>>(qkv, gates, Sloc, Aprod);
  // 4. chunk-level scan (parallel + batched loads)
  gl_scan_chunks<<<128, 128, 0, stream>>>(Sloc, Aprod, Sin);
  // 5. replay with incoming state, emit outputs
  gl_pass2<<<dim3(NCHUNK, NH), 256, 0, stream>>>(qkv, gates, Sin, out);
}

// Round 5
// 81.635 us; speedup vs baseline: 2.7758x; 1.0277x over previous
//
#include <hip/hip_runtime.h>
#include <hip/hip_bf16.h>

#define SEQ    4096
#define DIM    512
#define DIM3   1536
#define NH     16
#define HD     32
#define CHUNK  64
#define NCHUNK (SEQ / CHUNK)

typedef __attribute__((ext_vector_type(8))) short short8;
typedef __attribute__((ext_vector_type(4))) float f32x4;
typedef __attribute__((ext_vector_type(4))) unsigned short u16x4;

__device__ inline unsigned short f2bf(float f) {
  unsigned u = __builtin_bit_cast(unsigned, f);
  unsigned r = (u + 0x7fff + ((u >> 16) & 1)) >> 16;
  return (unsigned short)r;
}

// ---------------------------------------------------------------------------
// Kernel 0 (merged): blocks 0..2047   : x -> bf16
//                    blocks 2048..2815: W_qkv -> Wt bf16 transposed
//                    blocks 2816..3839: gates (f32-exact a_lin)
// ---------------------------------------------------------------------------
__global__ __launch_bounds__(256) void gl_cvt_gate(
    const float* __restrict__ x, const float* __restrict__ W,
    const float* __restrict__ Wa, const float* __restrict__ ba,
    unsigned short* __restrict__ xb, unsigned short* __restrict__ Wt,
    float2* __restrict__ gates) {
  __shared__ union {
    float wtile[32][33];
    struct { float xs[4][DIM]; float red[4][8][32]; } g;
  } sm;
  int b = blockIdx.x;
  if (b < 2048) {
    int i = b * 256 + threadIdx.x;
    float4 v = ((const float4*)x)[i];
    u16x4 o = {f2bf(v.x), f2bf(v.y), f2bf(v.z), f2bf(v.w)};
    ((u16x4*)xb)[i] = o;
  } else if (b < 2816) {
    b -= 2048;
    int bx = b % 48, by = b / 48;
    int tx = threadIdx.x & 31, ty = threadIdx.x >> 5;
    for (int i = ty; i < 32; i += 8)
      sm.wtile[i][tx] = W[(size_t)(by * 32 + i) * DIM3 + bx * 32 + tx];
    __syncthreads();
    for (int i = ty; i < 32; i += 8)
      Wt[(size_t)(bx * 32 + i) * DIM + by * 32 + tx] = f2bf(sm.wtile[tx][i]);
  } else {
    const int n0 = (b - 2816) * 4;
    const int tid = threadIdx.x;
    const float4* xv = (const float4*)(x + (size_t)n0 * DIM);
    float4* xsv = (float4*)&sm.g.xs[0][0];
    for (int i = tid; i < 512; i += 256) xsv[i] = xv[i];
    __syncthreads();
    const int o = tid & 31, s = tid >> 5;
    float pr[4] = {0, 0, 0, 0};
    for (int k = s * 64; k < s * 64 + 64; ++k) {
      float w = Wa[k * 32 + o];
      #pragma unroll
      for (int r = 0; r < 4; ++r) pr[r] += sm.g.xs[r][k] * w;
    }
    #pragma unroll
    for (int r = 0; r < 4; ++r) sm.g.red[r][s][o] = pr[r];
    __syncthreads();
    if (tid < 128) {
      int r = tid >> 5, oo = tid & 31;
      float acc = ba[oo];
      #pragma unroll
      for (int ss = 0; ss < 8; ++ss) acc += sm.g.red[r][ss][oo];
      sm.g.red[r][0][oo] = acc;
    }
    __syncthreads();
    if (tid < 64) {
      int r = tid >> 4, hh = tid & 15;
      float re = sm.g.red[r][0][2 * hh], im = sm.g.red[r][0][2 * hh + 1];
      float mag = sqrtf(re * re + im * im);
      float sig = 1.0f / (1.0f + expf(-mag));
      float2 g;
      if (mag < 1e-30f) g = make_float2(0.5f, 0.0f);
      else { float sc = sig / mag; g = make_float2(re * sc, im * sc); }
      gates[(size_t)hh * SEQ + n0 + r] = g;
    }
  }
}

// ---------------------------------------------------------------------------
// Kernel 1: qkv = x @ W_qkv, bf16 MFMA, 128x128 tile, BK=64.
// 2-phase double-buffered LDS + counted vmcnt(8): prefetch tile t+1 stays in
// flight across the barrier while computing tile t. Bijective XCD swizzle.
// ---------------------------------------------------------------------------
#define GBM 128
#define GBN 128
#define GBK 64
__global__ __launch_bounds__(256) void gl_gemm_mfma(
    const unsigned short* __restrict__ A, const unsigned short* __restrict__ Bt,
    float* __restrict__ C) {
  __shared__ unsigned short As[2][GBM * GBK];
  __shared__ unsigned short Bs[2][GBM * GBK];
  const int tid = threadIdx.x;
  const int id = blockIdx.x;
  const int tile = (id & 7) * 48 + (id >> 3);   // 384 = 8 XCDs x 48
  const int by = tile / 12, bx = tile % 12;
  const int row0 = by * GBM, col0 = bx * GBN;
  const int wid = tid >> 6, lane = tid & 63;
  const int wr = wid >> 1, wc = wid & 1;
  const int lr = lane & 15, lg = lane >> 4;

  auto stage = [&](int buf, int t) {
    const int k0 = t * GBK;
    #pragma unroll
    for (int i = 0; i < 4; ++i) {
      int byteoff = i * 4096 + tid * 16;
      int row = byteoff >> 7;
      int logslot = ((byteoff >> 4) & 7) ^ (row & 7);
      const unsigned short* gp = A + (size_t)(row0 + row) * DIM + k0 + logslot * 8;
      __builtin_amdgcn_global_load_lds(
          (const __attribute__((address_space(1))) void*)gp,
          (__attribute__((address_space(3))) void*)((char*)As[buf] + byteoff),
          16, 0, 0);
    }
    #pragma unroll
    for (int i = 0; i < 4; ++i) {
      int byteoff = i * 4096 + tid * 16;
      int row = byteoff >> 7;
      int logslot = ((byteoff >> 4) & 7) ^ (row & 7);
      const unsigned short* gp = Bt + (size_t)(col0 + row) * DIM + k0 + logslot * 8;
      __builtin_amdgcn_global_load_lds(
          (const __attribute__((address_space(1))) void*)gp,
          (__attribute__((address_space(3))) void*)((char*)Bs[buf] + byteoff),
          16, 0, 0);
    }
  };

  f32x4 acc[4][4] = {};
  stage(0, 0);

  #pragma unroll
  for (int t = 0; t < 8; ++t) {
    const int p = t & 1;
    if (t < 7) {
      stage(p ^ 1, t + 1);
      asm volatile("s_waitcnt vmcnt(8)" ::: "memory");  // tile t's 8 loads done
    } else {
      asm volatile("s_waitcnt vmcnt(0)" ::: "memory");
    }
    __syncthreads();
    const char* AsB = (const char*)As[p];
    const char* BsB = (const char*)Bs[p];
    #pragma unroll
    for (int ks = 0; ks < 2; ++ks) {
      short8 af[4], bfr[4];
      #pragma unroll
      for (int m = 0; m < 4; ++m) {
        int row = wr * 64 + m * 16 + lr;
        int ps = (ks * 4 + lg) ^ (row & 7);
        af[m] = *(const short8*)(AsB + row * 128 + ps * 16);
      }
      #pragma unroll
      for (int n = 0; n < 4; ++n) {
        int col = wc * 64 + n * 16 + lr;
        int ps = (ks * 4 + lg) ^ (col & 7);
        bfr[n] = *(const short8*)(BsB + col * 128 + ps * 16);
      }
      #pragma unroll
      for (int m = 0; m < 4; ++m)
        #pragma unroll
        for (int n = 0; n < 4; ++n)
          acc[m][n] = __builtin_amdgcn_mfma_f32_16x16x32_bf16(
              af[m], bfr[n], acc[m][n], 0, 0, 0);
    }
    __syncthreads();
  }

  #pragma unroll
  for (int m = 0; m < 4; ++m)
    #pragma unroll
    for (int n = 0; n < 4; ++n) {
      int grow0 = row0 + wr * 64 + m * 16 + lg * 4;
      int gcol = col0 + wc * 64 + n * 16 + lr;
      #pragma unroll
      for (int j = 0; j < 4; ++j)
        C[(size_t)(grow0 + j) * DIM3 + gcol] = acc[m][n][j];
    }
}

// ---------------------------------------------------------------------------
// Kernel 3 (pass 1): per (head, chunk) local end-state S_loc (complex 32x32)
// and cumulative gate product A_prod.
// ---------------------------------------------------------------------------
__global__ __launch_bounds__(256) void gl_pass1(
    const float* __restrict__ qkv, const float2* __restrict__ gates,
    float2* __restrict__ Sloc, float2* __restrict__ Aprod) {
  const int c = blockIdx.x;
  const int h = blockIdx.y;
  const int tid = threadIdx.x;
  __shared__ float ks[CHUNK][HD];
  __shared__ float vs[CHUNK][HD];
  __shared__ float2 as_[CHUNK];
  const int n0 = c * CHUNK;
  for (int i = tid; i < CHUNK * HD; i += 256) {
    int t = i >> 5, e = i & 31;
    size_t rowoff = (size_t)(n0 + t) * DIM3 + h * HD + e;
    ks[t][e] = qkv[rowoff + DIM];
    vs[t][e] = qkv[rowoff + 2 * DIM];
  }
  if (tid < CHUNK) as_[tid] = gates[(size_t)h * SEQ + n0 + tid];
  __syncthreads();

  const int base = tid * 4;
  const int d = base >> 5;
  const int e0 = base & 31;
  float sre[4] = {0, 0, 0, 0}, sim[4] = {0, 0, 0, 0};
  for (int t = 0; t < CHUNK; ++t) {
    float2 a = as_[t];
    float kd = ks[t][d];
    #pragma unroll
    for (int j = 0; j < 4; ++j) {
      float re = sre[j], im = sim[j];
      sre[j] = a.x * re - a.y * im + kd * vs[t][e0 + j];
      sim[j] = a.y * re + a.x * im;
    }
  }
  float2* outp = Sloc + (size_t)(h * NCHUNK + c) * (HD * HD);
  #pragma unroll
  for (int j = 0; j < 4; ++j) outp[base + j] = make_float2(sre[j], sim[j]);

  if (tid == 0) {
    float2 p = make_float2(1.0f, 0.0f);
    for (int t = 0; t < CHUNK; ++t) {
      float2 a = as_[t];
      p = make_float2(p.x * a.x - p.y * a.y, p.x * a.y + p.y * a.x);
    }
    Aprod[h * NCHUNK + c] = p;
  }
}

// ---------------------------------------------------------------------------
// Kernel 4: chunk-level scan: 128 blocks (16 heads x 8 octants), 128 threads,
// 8-deep load batching for latency pipelining.
// ---------------------------------------------------------------------------
__global__ __launch_bounds__(128) void gl_scan_chunks(
    const float2* __restrict__ Sloc, const float2* __restrict__ Aprod,
    float2* __restrict__ Sin) {
  const int h = blockIdx.x >> 3;
  const int oct = blockIdx.x & 7;
  const int elem = oct * 128 + threadIdx.x;
  const float2* SL = Sloc + (size_t)h * NCHUNK * (HD * HD) + elem;
  float2* SI = Sin + (size_t)h * NCHUNK * (HD * HD) + elem;
  const float2* AP = Aprod + h * NCHUNK;
  float2 s = make_float2(0.0f, 0.0f);
  for (int cg = 0; cg < NCHUNK; cg += 8) {
    float2 l[8], a[8];
    #pragma unroll
    for (int j = 0; j < 8; ++j) {
      l[j] = SL[(size_t)(cg + j) * (HD * HD)];
      a[j] = AP[cg + j];
    }
    #pragma unroll
    for (int j = 0; j < 8; ++j) {
      SI[(size_t)(cg + j) * (HD * HD)] = s;
      float re = s.x, im = s.y;
      s.x = a[j].x * re - a[j].y * im + l[j].x;
      s.y = a[j].x * im + a[j].y * re + l[j].y;
    }
  }
}

// ---------------------------------------------------------------------------
// Kernel 5 (pass 2): replay each chunk with incoming state, emit outputs
// ---------------------------------------------------------------------------
__global__ __launch_bounds__(256) void gl_pass2(
    const float* __restrict__ qkv, const float2* __restrict__ gates,
    const float2* __restrict__ Sin, float* __restrict__ out) {
  const int c = blockIdx.x;
  const int h = blockIdx.y;
  const int tid = threadIdx.x;
  __shared__ float qs[CHUNK][HD];
  __shared__ float ks[CHUNK][HD];
  __shared__ float vs[CHUNK][HD];
  __shared__ float os[CHUNK][HD];
  __shared__ float2 as_[CHUNK];
  const int n0 = c * CHUNK;
  for (int i = tid; i < CHUNK * HD; i += 256) {
    int t = i >> 5, e = i & 31;
    size_t rowoff = (size_t)(n0 + t) * DIM3 + h * HD + e;
    qs[t][e] = qkv[rowoff];
    ks[t][e] = qkv[rowoff + DIM];
    vs[t][e] = qkv[rowoff + 2 * DIM];
  }
  if (tid < CHUNK) as_[tid] = gates[(size_t)h * SEQ + n0 + tid];
  __syncthreads();

  const int e = tid >> 3;
  const int dsub = tid & 7;
  const int d0 = dsub * 4;
  float sre[4], sim[4];
  const size_t soff = (size_t)(h * NCHUNK + c) * (HD * HD);
  #pragma unroll
  for (int j = 0; j < 4; ++j) {
    float2 sv = Sin[soff + (size_t)(d0 + j) * HD + e];
    sre[j] = sv.x;
    sim[j] = sv.y;
  }
  for (int t = 0; t < CHUNK; ++t) {
    float2 a = as_[t];
    float ve = vs[t][e];
    float partial = 0.0f;
    #pragma unroll
    for (int j = 0; j < 4; ++j) {
      float kd = ks[t][d0 + j];
      float re = sre[j], im = sim[j];
      sre[j] = a.x * re - a.y * im + kd * ve;
      sim[j] = a.y * re + a.x * im;
      partial += qs[t][d0 + j] * sre[j];
    }
    partial += __shfl_xor(partial, 1);
    partial += __shfl_xor(partial, 2);
    partial += __shfl_xor(partial, 4);
    if (dsub == 0) os[t][e] = partial;
  }
  __syncthreads();
  for (int i = tid; i < CHUNK * HD; i += 256) {
    int t = i >> 5, ee = i & 31;
    out[(size_t)(n0 + t) * DIM + h * HD + ee] = os[t][ee];
  }
}

// ---------------------------------------------------------------------------
extern "C" void kernel_launch(void* const* d_in, const int* in_sizes, int n_in,
                              void* d_out, int out_size, void* d_ws,
                              size_t ws_size, hipStream_t stream) {
  const float* x     = (const float*)d_in[0];
  const float* W_qkv = (const float*)d_in[1];
  const float* W_a   = (const float*)d_in[2];
  const float* b_a   = (const float*)d_in[3];
  float* out = (float*)d_out;

  char* ws = (char*)d_ws;
  float*          qkv   = (float*)ws;                         // 25165824 B
  float2*         gates = (float2*)(ws + 25165824);           // 524288 B
  float2*         Sloc  = (float2*)(ws + 25690112);           // 8388608 B
  float2*         Aprod = (float2*)(ws + 34078720);           // 8192 B
  float2*         Sin   = (float2*)(ws + 34086912);           // 8388608 B
  unsigned short* xb    = (unsigned short*)(ws + 42475520);   // 4194304 B
  unsigned short* Wt    = (unsigned short*)(ws + 46669824);   // 1572864 B

  // 0. conversions + gates (independent of GEMM)
  gl_cvt_gate<<<3840, 256, 0, stream>>>(x, W_qkv, W_a, b_a, xb, Wt, gates);
  // 1. qkv GEMM (MFMA bf16, 2-phase pipelined)
  gl_gemm_mfma<<<384, 256, 0, stream>>>(xb, Wt, qkv);
  // 3. per-chunk local scan
  gl_pass1<<<dim3(NCHUNK, NH), 256, 0, stream>>>(qkv, gates, Sloc, Aprod);
  // 4. chunk-level scan
  gl_scan_chunks<<<128, 128, 0, stream>>>(Sloc, Aprod, Sin);
  // 5. replay with incoming state, emit outputs
  gl_pass2<<<dim3(NCHUNK, NH), 256, 0, stream>>>(qkv, gates, Sin, out);
}

// Round 6
// 51.879 us; speedup vs baseline: 4.3680x; 1.5736x over previous
//
#include <hip/hip_runtime.h>
#include <hip/hip_bf16.h>

#define SEQ    4096
#define DIM    512
#define DIM3   1536
#define NH     16
#define HD     32
#define CHUNK  64
#define NCHUNK (SEQ / CHUNK)

typedef __attribute__((ext_vector_type(8))) short short8;
typedef __attribute__((ext_vector_type(4))) float f32x4;
typedef __attribute__((ext_vector_type(4))) unsigned short u16x4;
typedef __attribute__((ext_vector_type(4))) unsigned int u32x4;

__device__ inline unsigned short f2bf(float f) {
  unsigned u = __builtin_bit_cast(unsigned, f);
  unsigned r = (u + 0x7fff + ((u >> 16) & 1)) >> 16;
  return (unsigned short)r;
}
__device__ inline float bf2f(unsigned short b) {
  unsigned u = ((unsigned)b) << 16;
  return __builtin_bit_cast(float, u);
}

// ---------------------------------------------------------------------------
// Kernel 0: blocks 0..2047: x->bf16 | 2048..2815: W_qkv -> Wt bf16 transposed
//           | 2816..3839: gates as (ln sigmoid(|a|), angle(a))  [f32-exact]
// ---------------------------------------------------------------------------
__global__ __launch_bounds__(256) void gl_cvt_gate(
    const float* __restrict__ x, const float* __restrict__ W,
    const float* __restrict__ Wa, const float* __restrict__ ba,
    unsigned short* __restrict__ xb, unsigned short* __restrict__ Wt,
    float2* __restrict__ graw) {
  __shared__ union {
    float wtile[32][33];
    struct { float xs[4][DIM]; float red[4][8][32]; } g;
  } sm;
  int b = blockIdx.x;
  if (b < 2048) {
    int i = b * 256 + threadIdx.x;
    float4 v = ((const float4*)x)[i];
    u16x4 o = {f2bf(v.x), f2bf(v.y), f2bf(v.z), f2bf(v.w)};
    ((u16x4*)xb)[i] = o;
  } else if (b < 2816) {
    b -= 2048;
    int bx = b % 48, by = b / 48;
    int tx = threadIdx.x & 31, ty = threadIdx.x >> 5;
    for (int i = ty; i < 32; i += 8)
      sm.wtile[i][tx] = W[(size_t)(by * 32 + i) * DIM3 + bx * 32 + tx];
    __syncthreads();
    for (int i = ty; i < 32; i += 8)
      Wt[(size_t)(bx * 32 + i) * DIM + by * 32 + tx] = f2bf(sm.wtile[tx][i]);
  } else {
    const int n0 = (b - 2816) * 4;
    const int tid = threadIdx.x;
    const float4* xv = (const float4*)(x + (size_t)n0 * DIM);
    float4* xsv = (float4*)&sm.g.xs[0][0];
    for (int i = tid; i < 512; i += 256) xsv[i] = xv[i];
    __syncthreads();
    const int o = tid & 31, s = tid >> 5;
    float pr[4] = {0, 0, 0, 0};
    for (int k = s * 64; k < s * 64 + 64; ++k) {
      float w = Wa[k * 32 + o];
      #pragma unroll
      for (int r = 0; r < 4; ++r) pr[r] += sm.g.xs[r][k] * w;
    }
    #pragma unroll
    for (int r = 0; r < 4; ++r) sm.g.red[r][s][o] = pr[r];
    __syncthreads();
    if (tid < 128) {
      int r = tid >> 5, oo = tid & 31;
      float acc = ba[oo];
      #pragma unroll
      for (int ss = 0; ss < 8; ++ss) acc += sm.g.red[r][ss][oo];
      sm.g.red[r][0][oo] = acc;
    }
    __syncthreads();
    if (tid < 64) {
      int r = tid >> 4, hh = tid & 15;
      float re = sm.g.red[r][0][2 * hh], im = sm.g.red[r][0][2 * hh + 1];
      float mag = sqrtf(re * re + im * im);
      float lml = -log1pf(expf(-mag));      // ln sigmoid(mag)
      float ph = atan2f(im, re);            // angle
      graw[(size_t)hh * SEQ + n0 + r] = make_float2(lml, ph);
    }
  }
}

// ---------------------------------------------------------------------------
// Kernel 1: qkv(bf16) = x @ W_qkv, bf16 MFMA, 128x128, BK=64, 2-phase dbuf
// with counted vmcnt(8); bijective XCD swizzle.
// ---------------------------------------------------------------------------
#define GBM 128
#define GBN 128
#define GBK 64
__global__ __launch_bounds__(256) void gl_gemm_mfma(
    const unsigned short* __restrict__ A, const unsigned short* __restrict__ Bt,
    unsigned short* __restrict__ C) {
  __shared__ unsigned short As[2][GBM * GBK];
  __shared__ unsigned short Bs[2][GBM * GBK];
  const int tid = threadIdx.x;
  const int id = blockIdx.x;
  const int tile = (id & 7) * 48 + (id >> 3);
  const int by = tile / 12, bx = tile % 12;
  const int row0 = by * GBM, col0 = bx * GBN;
  const int wid = tid >> 6, lane = tid & 63;
  const int wr = wid >> 1, wc = wid & 1;
  const int lr = lane & 15, lg = lane >> 4;

  auto stage = [&](int buf, int t) {
    const int k0 = t * GBK;
    #pragma unroll
    for (int i = 0; i < 4; ++i) {
      int byteoff = i * 4096 + tid * 16;
      int row = byteoff >> 7;
      int logslot = ((byteoff >> 4) & 7) ^ (row & 7);
      const unsigned short* gp = A + (size_t)(row0 + row) * DIM + k0 + logslot * 8;
      __builtin_amdgcn_global_load_lds(
          (const __attribute__((address_space(1))) void*)gp,
          (__attribute__((address_space(3))) void*)((char*)As[buf] + byteoff),
          16, 0, 0);
    }
    #pragma unroll
    for (int i = 0; i < 4; ++i) {
      int byteoff = i * 4096 + tid * 16;
      int row = byteoff >> 7;
      int logslot = ((byteoff >> 4) & 7) ^ (row & 7);
      const unsigned short* gp = Bt + (size_t)(col0 + row) * DIM + k0 + logslot * 8;
      __builtin_amdgcn_global_load_lds(
          (const __attribute__((address_space(1))) void*)gp,
          (__attribute__((address_space(3))) void*)((char*)Bs[buf] + byteoff),
          16, 0, 0);
    }
  };

  f32x4 acc[4][4] = {};
  stage(0, 0);

  #pragma unroll
  for (int t = 0; t < 8; ++t) {
    const int p = t & 1;
    if (t < 7) {
      stage(p ^ 1, t + 1);
      asm volatile("s_waitcnt vmcnt(8)" ::: "memory");
    } else {
      asm volatile("s_waitcnt vmcnt(0)" ::: "memory");
    }
    __syncthreads();
    const char* AsB = (const char*)As[p];
    const char* BsB = (const char*)Bs[p];
    #pragma unroll
    for (int ks = 0; ks < 2; ++ks) {
      short8 af[4], bfr[4];
      #pragma unroll
      for (int m = 0; m < 4; ++m) {
        int row = wr * 64 + m * 16 + lr;
        int ps = (ks * 4 + lg) ^ (row & 7);
        af[m] = *(const short8*)(AsB + row * 128 + ps * 16);
      }
      #pragma unroll
      for (int n = 0; n < 4; ++n) {
        int col = wc * 64 + n * 16 + lr;
        int ps = (ks * 4 + lg) ^ (col & 7);
        bfr[n] = *(const short8*)(BsB + col * 128 + ps * 16);
      }
      #pragma unroll
      for (int m = 0; m < 4; ++m)
        #pragma unroll
        for (int n = 0; n < 4; ++n)
          acc[m][n] = __builtin_amdgcn_mfma_f32_16x16x32_bf16(
              af[m], bfr[n], acc[m][n], 0, 0, 0);
    }
    __syncthreads();
  }

  #pragma unroll
  for (int m = 0; m < 4; ++m)
    #pragma unroll
    for (int n = 0; n < 4; ++n) {
      int grow0 = row0 + wr * 64 + m * 16 + lg * 4;
      int gcol = col0 + wc * 64 + n * 16 + lr;
      #pragma unroll
      for (int j = 0; j < 4; ++j)
        C[(size_t)(grow0 + j) * DIM3 + gcol] = f2bf(acc[m][n][j]);
    }
}

// ---------------------------------------------------------------------------
// Kernel 2 (pass1, MFMA): per (h,c): chunk-local prefix (Lm,Ph) via shfl scan;
// S_loc = (w∘K)^T V with w_j = suffix gate product, via 16x16x32 MFMA.
// wave0 -> real part, wave1 -> imag part. Also emits Aprod and LmPh.
// ---------------------------------------------------------------------------
__global__ __launch_bounds__(128) void gl_pass1(
    const unsigned short* __restrict__ qkv, const float2* __restrict__ graw,
    float2* __restrict__ LmPh, float* __restrict__ SLre,
    float* __restrict__ SLim, float2* __restrict__ Aprod) {
  const int b = blockIdx.x;
  const int c = b & (NCHUNK - 1), h = b >> 6;
  const int tid = threadIdx.x, w = tid >> 6, lane = tid & 63;
  const int lr = lane & 15, lg = lane >> 4;
  const int n0 = c * CHUNK;
  __shared__ float2 lmph[CHUNK];

  float2 g = graw[(size_t)h * SEQ + n0 + lane];
  float lm = g.x, ph = g.y;
  #pragma unroll
  for (int off = 1; off < 64; off <<= 1) {
    float a = __shfl_up(lm, off), p = __shfl_up(ph, off);
    if (lane >= off) { lm += a; ph += p; }
  }
  if (w == 0) {
    LmPh[(size_t)h * SEQ + n0 + lane] = make_float2(lm, ph);
    lmph[lane] = make_float2(lm, ph);
    if (lane == 63) {
      float e = __expf(lm);
      Aprod[h * NCHUNK + c] = make_float2(e * __cosf(ph), e * __sinf(ph));
    }
  }
  __syncthreads();
  const float2 end = lmph[63];

  const size_t rowb = (size_t)n0 * DIM3 + h * HD;
  f32x4 acc[2][2] = {};
  #pragma unroll
  for (int ks = 0; ks < 2; ++ks) {
    const int jb = ks * 32 + lg * 8;
    float wv[8];
    #pragma unroll
    for (int jj = 0; jj < 8; ++jj) {
      float2 lp = lmph[jb + jj];
      float e = __expf(end.x - lp.x);
      float an = end.y - lp.y;
      wv[jj] = e * (w == 0 ? __cosf(an) : __sinf(an));
    }
    short8 afr[2], bfr[2];
    #pragma unroll
    for (int mt = 0; mt < 2; ++mt) {
      int d = mt * 16 + lr;
      unsigned u0, u1, u2, u3;
      #define LD_KW(q) ((unsigned)f2bf(bf2f(qkv[rowb + (size_t)(jb + 2*(q)) * DIM3 + DIM + d]) * wv[2*(q)]) | \
                        ((unsigned)f2bf(bf2f(qkv[rowb + (size_t)(jb + 2*(q)+1) * DIM3 + DIM + d]) * wv[2*(q)+1]) << 16))
      u0 = LD_KW(0); u1 = LD_KW(1); u2 = LD_KW(2); u3 = LD_KW(3);
      #undef LD_KW
      u32x4 t = {u0, u1, u2, u3};
      afr[mt] = __builtin_bit_cast(short8, t);
    }
    #pragma unroll
    for (int nt = 0; nt < 2; ++nt) {
      int e_ = nt * 16 + lr;
      unsigned u0, u1, u2, u3;
      #define LD_V(q) ((unsigned)qkv[rowb + (size_t)(jb + 2*(q)) * DIM3 + 2*DIM + e_] | \
                       ((unsigned)qkv[rowb + (size_t)(jb + 2*(q)+1) * DIM3 + 2*DIM + e_] << 16))
      u0 = LD_V(0); u1 = LD_V(1); u2 = LD_V(2); u3 = LD_V(3);
      #undef LD_V
      u32x4 t = {u0, u1, u2, u3};
      bfr[nt] = __builtin_bit_cast(short8, t);
    }
    #pragma unroll
    for (int mt = 0; mt < 2; ++mt)
      #pragma unroll
      for (int nt = 0; nt < 2; ++nt)
        acc[mt][nt] = __builtin_amdgcn_mfma_f32_16x16x32_bf16(
            afr[mt], bfr[nt], acc[mt][nt], 0, 0, 0);
  }
  float* dst = (w == 0) ? SLre : SLim;
  const size_t base = (size_t)(h * NCHUNK + c) * (HD * HD);
  #pragma unroll
  for (int mt = 0; mt < 2; ++mt)
    #pragma unroll
    for (int nt = 0; nt < 2; ++nt)
      #pragma unroll
      for (int r = 0; r < 4; ++r) {
        int d = mt * 16 + lg * 4 + r, e_ = nt * 16 + lr;
        dst[base + d * HD + e_] = acc[mt][nt][r];
      }
}

// ---------------------------------------------------------------------------
// Kernel 3: chunk-level scan (unchanged structure, split re/im Sloc inputs)
// ---------------------------------------------------------------------------
__global__ __launch_bounds__(128) void gl_scan_chunks(
    const float* __restrict__ SLre, const float* __restrict__ SLim,
    const float2* __restrict__ Aprod, float2* __restrict__ Sin) {
  const int h = blockIdx.x >> 3;
  const int oct = blockIdx.x & 7;
  const size_t hb = (size_t)h * NCHUNK * (HD * HD) + oct * 128 + threadIdx.x;
  const float2* AP = Aprod + h * NCHUNK;
  float2 s = make_float2(0.f, 0.f);
  for (int cg = 0; cg < NCHUNK; cg += 8) {
    float lre[8], lim[8];
    float2 a[8];
    #pragma unroll
    for (int j = 0; j < 8; ++j) {
      size_t off = hb + (size_t)(cg + j) * (HD * HD);
      lre[j] = SLre[off];
      lim[j] = SLim[off];
      a[j] = AP[cg + j];
    }
    #pragma unroll
    for (int j = 0; j < 8; ++j) {
      Sin[hb + (size_t)(cg + j) * (HD * HD)] = s;
      float re = s.x, im = s.y;
      s.x = a[j].x * re - a[j].y * im + lre[j];
      s.y = a[j].x * im + a[j].y * re + lim[j];
    }
  }
}

// ---------------------------------------------------------------------------
// Kernel 4 (pass2, MFMA): per (h,c):
//   P^T = K Q^T (MFMA) -> weight W(n,j)=1[j<=n]exp(Lm_n-Lm_j)cos(Ph_n-Ph_j),
//   pack bf16 j-pairs -> LDS Pp; O = Re(G_n (Q S_in)) + (P∘W) V  (all MFMA).
// 2 waves split the j-tiles (P^T) / n-tiles (QS, PV).
// ---------------------------------------------------------------------------
__global__ __launch_bounds__(128) void gl_pass2(
    const unsigned short* __restrict__ qkv, const float2* __restrict__ LmPh,
    const float2* __restrict__ Sin, float* __restrict__ out) {
  const int b = blockIdx.x;
  const int c = b & (NCHUNK - 1), h = b >> 6;
  const int tid = threadIdx.x, w = tid >> 6, lane = tid & 63;
  const int lr = lane & 15, lg = lane >> 4;
  const int n0 = c * CHUNK;
  __shared__ float2 lmph[CHUNK];
  __shared__ unsigned Pp[32][68];   // packed bf16 j-pairs, padded (bank-clean)
  if (tid < 64) lmph[tid] = LmPh[(size_t)h * SEQ + n0 + tid];
  __syncthreads();

  const size_t rowb = (size_t)n0 * DIM3 + h * HD;
  // K fragments (this wave's 2 j-tiles), Q fragments (all 4 n-tiles)
  short8 kf[2], qf[4];
  #pragma unroll
  for (int mt = 0; mt < 2; ++mt) {
    int j = (2 * w + mt) * 16 + lr;
    kf[mt] = *(const short8*)(qkv + rowb + (size_t)j * DIM3 + DIM + lg * 8);
  }
  #pragma unroll
  for (int nt = 0; nt < 4; ++nt) {
    int n = nt * 16 + lr;
    qf[nt] = *(const short8*)(qkv + rowb + (size_t)n * DIM3 + lg * 8);
  }
  // P^T = K @ Q^T
  f32x4 pacc[2][4] = {};
  #pragma unroll
  for (int mt = 0; mt < 2; ++mt)
    #pragma unroll
    for (int nt = 0; nt < 4; ++nt)
      pacc[mt][nt] = __builtin_amdgcn_mfma_f32_16x16x32_bf16(
          kf[mt], qf[nt], pacc[mt][nt], 0, 0, 0);

  // weight + pack to LDS
  #pragma unroll
  for (int mt = 0; mt < 2; ++mt) {
    int jt = 2 * w + mt;
    #pragma unroll
    for (int r2 = 0; r2 < 2; ++r2) {
      int j0 = jt * 16 + lg * 4 + 2 * r2;
      float2 lj0 = lmph[j0], lj1 = lmph[j0 + 1];
      #pragma unroll
      for (int nt = 0; nt < 4; ++nt) {
        int n = nt * 16 + lr;
        float2 ln = lmph[n];
        float w0 = (j0 <= n) ? __expf(ln.x - lj0.x) * __cosf(ln.y - lj0.y) : 0.f;
        float w1 = (j0 + 1 <= n) ? __expf(ln.x - lj1.x) * __cosf(ln.y - lj1.y) : 0.f;
        Pp[jt * 8 + lg * 2 + r2][n] =
            (unsigned)f2bf(pacc[mt][nt][2 * r2] * w0) |
            ((unsigned)f2bf(pacc[mt][nt][2 * r2 + 1] * w1) << 16);
      }
    }
  }
  __syncthreads();

  // inter: QS = Q @ S_in (re & im)
  const size_t soff = (size_t)(h * NCHUNK + c) * (HD * HD);
  short8 sre[2], sim[2];
  #pragma unroll
  for (int nt = 0; nt < 2; ++nt) {
    int e_ = nt * 16 + lr;
    unsigned ur[4], ui[4];
    #pragma unroll
    for (int q = 0; q < 4; ++q) {
      float2 s0 = Sin[soff + (size_t)(lg * 8 + 2 * q) * HD + e_];
      float2 s1 = Sin[soff + (size_t)(lg * 8 + 2 * q + 1) * HD + e_];
      ur[q] = (unsigned)f2bf(s0.x) | ((unsigned)f2bf(s1.x) << 16);
      ui[q] = (unsigned)f2bf(s0.y) | ((unsigned)f2bf(s1.y) << 16);
    }
    u32x4 tr = {ur[0], ur[1], ur[2], ur[3]};
    u32x4 ti = {ui[0], ui[1], ui[2], ui[3]};
    sre[nt] = __builtin_bit_cast(short8, tr);
    sim[nt] = __builtin_bit_cast(short8, ti);
  }
  f32x4 ore[2][2] = {}, oim[2][2] = {};
  #pragma unroll
  for (int mt = 0; mt < 2; ++mt)
    #pragma unroll
    for (int nt = 0; nt < 2; ++nt) {
      ore[mt][nt] = __builtin_amdgcn_mfma_f32_16x16x32_bf16(
          qf[2 * w + mt], sre[nt], ore[mt][nt], 0, 0, 0);
      oim[mt][nt] = __builtin_amdgcn_mfma_f32_16x16x32_bf16(
          qf[2 * w + mt], sim[nt], oim[mt][nt], 0, 0, 0);
    }
  // scale by G_n -> O accumulator init
  f32x4 oacc[2][2];
  #pragma unroll
  for (int mt = 0; mt < 2; ++mt)
    #pragma unroll
    for (int r = 0; r < 4; ++r) {
      int n = (2 * w + mt) * 16 + lg * 4 + r;
      float2 ln = lmph[n];
      float eg = __expf(ln.x);
      float gr = eg * __cosf(ln.y), gi = eg * __sinf(ln.y);
      oacc[mt][0][r] = gr * ore[mt][0][r] - gi * oim[mt][0][r];
      oacc[mt][1][r] = gr * ore[mt][1][r] - gi * oim[mt][1][r];
    }
  // intra: O += (P∘W) V
  #pragma unroll
  for (int ks = 0; ks < 2; ++ks) {
    short8 pa[2];
    #pragma unroll
    for (int mt = 0; mt < 2; ++mt) {
      int n_ = (2 * w + mt) * 16 + lr;
      unsigned u0 = Pp[ks * 16 + lg * 4 + 0][n_];
      unsigned u1 = Pp[ks * 16 + lg * 4 + 1][n_];
      unsigned u2 = Pp[ks * 16 + lg * 4 + 2][n_];
      unsigned u3 = Pp[ks * 16 + lg * 4 + 3][n_];
      u32x4 t = {u0, u1, u2, u3};
      pa[mt] = __builtin_bit_cast(short8, t);
    }
    const int jb = ks * 32 + lg * 8;
    short8 vf[2];
    #pragma unroll
    for (int nt = 0; nt < 2; ++nt) {
      int e_ = nt * 16 + lr;
      unsigned u0, u1, u2, u3;
      #define LD_V(q) ((unsigned)qkv[rowb + (size_t)(jb + 2*(q)) * DIM3 + 2*DIM + e_] | \
                       ((unsigned)qkv[rowb + (size_t)(jb + 2*(q)+1) * DIM3 + 2*DIM + e_] << 16))
      u0 = LD_V(0); u1 = LD_V(1); u2 = LD_V(2); u3 = LD_V(3);
      #undef LD_V
      u32x4 t = {u0, u1, u2, u3};
      vf[nt] = __builtin_bit_cast(short8, t);
    }
    #pragma unroll
    for (int mt = 0; mt < 2; ++mt)
      #pragma unroll
      for (int nt = 0; nt < 2; ++nt)
        oacc[mt][nt] = __builtin_amdgcn_mfma_f32_16x16x32_bf16(
            pa[mt], vf[nt], oacc[mt][nt], 0, 0, 0);
  }
  // store
  #pragma unroll
  for (int mt = 0; mt < 2; ++mt)
    #pragma unroll
    for (int nt = 0; nt < 2; ++nt)
      #pragma unroll
      for (int r = 0; r < 4; ++r) {
        int n = (2 * w + mt) * 16 + lg * 4 + r;
        int e_ = nt * 16 + lr;
        out[(size_t)(n0 + n) * DIM + h * HD + e_] = oacc[mt][nt][r];
      }
}

// ---------------------------------------------------------------------------
extern "C" void kernel_launch(void* const* d_in, const int* in_sizes, int n_in,
                              void* d_out, int out_size, void* d_ws,
                              size_t ws_size, hipStream_t stream) {
  const float* x     = (const float*)d_in[0];
  const float* W_qkv = (const float*)d_in[1];
  const float* W_a   = (const float*)d_in[2];
  const float* b_a   = (const float*)d_in[3];
  float* out = (float*)d_out;

  char* ws = (char*)d_ws;
  unsigned short* qkv  = (unsigned short*)ws;               // 12,582,912 B
  float2* graw  = (float2*)(ws + 12582912);                 //    524,288 B
  float2* LmPh  = (float2*)(ws + 13107200);                 //    524,288 B
  float*  SLre  = (float*)(ws + 13631488);                  //  4,194,304 B
  float*  SLim  = (float*)(ws + 17825792);                  //  4,194,304 B
  float2* Aprod = (float2*)(ws + 22020096);                 //      8,192 B
  float2* Sin   = (float2*)(ws + 22028288);                 //  8,388,608 B
  unsigned short* xb = (unsigned short*)(ws + 30416896);    //  4,194,304 B
  unsigned short* Wt = (unsigned short*)(ws + 34611200);    //  1,572,864 B

  gl_cvt_gate<<<3840, 256, 0, stream>>>(x, W_qkv, W_a, b_a, xb, Wt, graw);
  gl_gemm_mfma<<<384, 256, 0, stream>>>(xb, Wt, qkv);
  gl_pass1<<<NCHUNK * NH, 128, 0, stream>>>(qkv, graw, LmPh, SLre, SLim, Aprod);
  gl_scan_chunks<<<128, 128, 0, stream>>>(SLre, SLim, Aprod, Sin);
  gl_pass2<<<NCHUNK * NH, 128, 0, stream>>>(qkv, LmPh, Sin, out);
}